// Round 2
// 1578.426 us; speedup vs baseline: 1.2824x; 1.2824x over previous
//
#include <hip/hip_runtime.h>
#include <stdint.h>

// Problem constants (reference: T=1000, N=64, H=1024, C=256)
#define T_STEPS 1000
#define NB      64
#define HDIM    1024
#define CDIM    256
#define G3      768          // 3*C
#define LOG2E   1.44269504088896340736f

typedef float f32x4  __attribute__((ext_vector_type(4)));
typedef short bf16x8 __attribute__((ext_vector_type(8)));   // 8 bf16 in 4 VGPRs
typedef int   i32x4  __attribute__((ext_vector_type(4)));   // 16 int8 in 4 VGPRs

__device__ __forceinline__ float bf2f(unsigned short u) {
    union { unsigned int i; float f; } v; v.i = ((unsigned int)u) << 16; return v.f;
}
__device__ __forceinline__ unsigned short f2bf(float f) {
    union { float f; unsigned int i; } v; v.f = f;
    unsigned int r = v.i + 0x7fffu + ((v.i >> 16) & 1u);   // RNE
    return (unsigned short)(r >> 16);
}

// Merge lower-32-lane halves of (x01, x23): result lanes 0-31 = x01 lanes 0-31,
// result lanes 32-63 = x23 lanes 0-31.
__device__ __forceinline__ int lane32_merge(int x01, int x23) {
#if __has_builtin(__builtin_amdgcn_permlane32_swap)
    // permlane32_swap: vdst[32:64] <-> vsrc[0:32]; ret[0] = new vdst.
    auto r = __builtin_amdgcn_permlane32_swap(x01, x23, false, false);
    return r[0];
#else
    const int lane = threadIdx.x & 63;
    const int lo = __shfl(x23, lane & 31, 64);   // x23[lane-32] for upper lanes
    return (lane < 32) ? x01 : lo;
#endif
}

// ---------------------------------------------------------------------------
// K0: convert W_ih [768,1024] fp32 -> bf16
// ---------------------------------------------------------------------------
__global__ __launch_bounds__(256) void cvt_wih(
    const float* __restrict__ wih, unsigned short* __restrict__ wih_bf)
{
    int idx = blockIdx.x * 256 + threadIdx.x;          // grid covers exactly 786432
    wih_bf[idx] = f2bf(wih[idx]);
}

// ---------------------------------------------------------------------------
// K0b: per-row symmetric int8 quantization of W_hh [768,256].
// ---------------------------------------------------------------------------
__global__ __launch_bounds__(64) void quant_whh(
    const float* __restrict__ whh, signed char* __restrict__ wq,
    float* __restrict__ dscale)
{
    const int g    = blockIdx.x;          // 0..767
    const int lane = threadIdx.x;         // 0..63
    const float4 w = *(const float4*)(whh + (size_t)g * CDIM + lane * 4);
    float m = fmaxf(fmaxf(fabsf(w.x), fabsf(w.y)), fmaxf(fabsf(w.z), fabsf(w.w)));
    #pragma unroll
    for (int s = 32; s > 0; s >>= 1) m = fmaxf(m, __shfl_xor(m, s, 64));
    const float inv = (m > 0.f) ? 127.f / m : 0.f;
    char4 q;
    q.x = (signed char)(int)rintf(w.x * inv);
    q.y = (signed char)(int)rintf(w.y * inv);
    q.z = (signed char)(int)rintf(w.z * inv);
    q.w = (signed char)(int)rintf(w.w * inv);
    *(char4*)(wq + (size_t)g * CDIM + lane * 4) = q;
    if (lane == 0) dscale[g] = m / (127.f * 127.f);
}

// ---------------------------------------------------------------------------
// K1: xp2[t][wgslab][g][n4] (bf16) = enc[t,4*wgslab+n4,:] . W_ih[g,:] + b_ih[g]
// 16-slab layout (4 batch rows per scan-WG). 256 thr, M=64,G=64,BK=64.
// ---------------------------------------------------------------------------
__global__ __launch_bounds__(256) void xproj_gemm(
    const float* __restrict__ enc,            // [64000,1024] fp32
    const unsigned short* __restrict__ wih,   // [768,1024] bf16
    const float* __restrict__ bih,            // [768] fp32
    unsigned short* __restrict__ xp2)         // [1000][16][768][4] bf16
{
    const int gt_base = blockIdx.x * 64;      // G-tile base (12 tiles)
    const int t       = blockIdx.y;           // M-tile == timestep (1000)
    const int tid  = threadIdx.x;
    const int w    = tid >> 6;                // wave 0..3 -> M rows [16w,16w+16)
    const int lane = tid & 63;
    const int q    = lane >> 4, l15 = lane & 15;

    __shared__ unsigned short As[64][72];
    __shared__ unsigned short Bs[64][72];

    const f32x4 zero4 = {0.f, 0.f, 0.f, 0.f};
    f32x4 acc[4] = {zero4, zero4, zero4, zero4};

    const int arow = tid >> 4;                // 0..15
    const int acol = (tid & 15) * 4;          // 0..60
    const int brow = tid >> 3;                // 0..31
    const int bcol = (tid & 7) * 8;           // 0..56

    for (int kt = 0; kt < 16; ++kt) {
        const int k0 = kt * 64;
        __syncthreads();
        #pragma unroll
        for (int i = 0; i < 4; ++i) {
            const int r = arow + i * 16;
            const float4 av = *(const float4*)(enc + (size_t)(t * 64 + r) * HDIM + k0 + acol);
            ushort4 u;
            u.x = f2bf(av.x); u.y = f2bf(av.y); u.z = f2bf(av.z); u.w = f2bf(av.w);
            *(ushort4*)(&As[r][acol]) = u;
        }
        #pragma unroll
        for (int i = 0; i < 2; ++i) {
            const int r = brow + i * 32;
            const uint4 bv = *(const uint4*)(wih + (size_t)(gt_base + r) * HDIM + k0 + bcol);
            *(uint4*)(&Bs[r][bcol]) = bv;
        }
        __syncthreads();
        #pragma unroll
        for (int kk = 0; kk < 2; ++kk) {
            const bf16x8 a = *(const bf16x8*)(&As[16 * w + l15][kk * 32 + q * 8]);
            #pragma unroll
            for (int g = 0; g < 4; ++g) {
                const bf16x8 b = *(const bf16x8*)(&Bs[16 * g + l15][kk * 32 + q * 8]);
                acc[g] = __builtin_amdgcn_mfma_f32_16x16x32_bf16(a, b, acc[g], 0, 0, 0);
            }
        }
    }

    // C row = 16w + 4q + r  ->  slab = 4w+q, subrow = r. ushort4 contiguous.
    #pragma unroll
    for (int g = 0; g < 4; ++g) {
        const int gg = gt_base + 16 * g + l15;
        const float bias = bih[gg];
        ushort4 u;
        u.x = f2bf(acc[g][0] + bias);
        u.y = f2bf(acc[g][1] + bias);
        u.z = f2bf(acc[g][2] + bias);
        u.w = f2bf(acc[g][3] + bias);
        *(ushort4*)(xp2 + ((size_t)((t * 16 + 4 * w + q) * G3 + gg)) * 4) = u;
    }
}

// ---------------------------------------------------------------------------
// K2: persistent GRU scan, int8 recurrent matvec.
// 16 WGs x 512 thr (8 waves). WG wg owns batch rows [4wg, 4wg+4) -- batch rows
// are independent, so WGs need no communication. MFMA M=16 is padded (rows
// 4..15 of hbuf stay zero from init; their C-rows are never consumed).
// Wave wv owns h col-tiles {2wv,2wv+1}. After the matvec, acc data lives only
// in lanes 0-15 (rows==regs); a lane-pack per (c,s) acc
// (2x shfl-bcast + 2x cndmask + permlane32_swap) redistributes
// reg r -> lane group q=r, so all 64 lanes do useful gate math (2 elems/lane
// instead of 8). W_hh int8 register-resident, pinned. h int8 in LDS,
// double-buffered; ONE lgkm-only barrier per step; xp prefetched 1 ahead.
// ---------------------------------------------------------------------------
__global__ void __launch_bounds__(512)
__attribute__((amdgpu_waves_per_eu(2, 2)))
gru_scan(
    const unsigned short* __restrict__ xp2,   // [1000][16][768][4] bf16
    const signed char* __restrict__ wq,       // [768][256] int8
    const float* __restrict__ dscale,         // [768] fp32
    const float* __restrict__ bhh,            // [768] fp32
    float* __restrict__ out)                  // [64000][256] fp32 (pre-softmax)
{
    const int wg   = blockIdx.x;              // 0..15
    const int tid  = threadIdx.x;
    const int wv   = tid >> 6;                // 0..7
    const int lane = tid & 63;
    const int q    = lane >> 4, l15 = lane & 15;

    // row stride 304 B (19*16): 16B-aligned rows, start-bank spread for b128
    __shared__ __align__(16) signed char hbuf[2][16][304];

    // Preload int8 W fragments. B-frag for 16x16x64 i8: B[n=l15][k=16q+j].
    i32x4 W[2][3][4];
    float d[2][3], bh[2][3];
    #pragma unroll
    for (int c = 0; c < 2; ++c)
        #pragma unroll
        for (int s = 0; s < 3; ++s) {
            const int g = 16 * (2 * wv + c) + 256 * s + l15;
            d[c][s]  = dscale[g];
            bh[c][s] = bhh[g];
            #pragma unroll
            for (int kk = 0; kk < 4; ++kk)
                W[c][s][kk] = *(const i32x4*)(wq + (size_t)g * CDIM + kk * 64 + q * 16);
        }
    #pragma unroll
    for (int c = 0; c < 2; ++c)
        #pragma unroll
        for (int s = 0; s < 3; ++s)
            asm volatile("" : "+v"(W[c][s][0]), "+v"(W[c][s][1]),
                              "+v"(W[c][s][2]), "+v"(W[c][s][3]));

    float h[2] = {0.f, 0.f};                  // h for (row q, col 32wv+16c+l15)

    for (int i = tid; i < 2 * 16 * 304; i += 512) ((signed char*)hbuf)[i] = 0;
    __syncthreads();

    // xp prefetch for t=0: 6 scalar bf16 elements per lane
    unsigned short xc[2][3];
    {
        const unsigned short* xpt = xp2 + (size_t)wg * (G3 * 4);
        #pragma unroll
        for (int c = 0; c < 2; ++c)
            #pragma unroll
            for (int s = 0; s < 3; ++s)
                xc[c][s] = xpt[(256 * s + 16 * (2 * wv + c) + l15) * 4 + q];
    }

    int pb = 0;
    for (int t = 0; t < T_STEPS; ++t) {
        // prefetch xp for t+1 (latency hides under MFMA + gate phase)
        const int tn = (t + 1 < T_STEPS) ? t + 1 : t;
        unsigned short xn_[2][3];
        {
            const unsigned short* xpt = xp2 + ((size_t)tn * 16 + wg) * (G3 * 4);
            #pragma unroll
            for (int c = 0; c < 2; ++c)
                #pragma unroll
                for (int s = 0; s < 3; ++s)
                    xn_[c][s] = xpt[(256 * s + 16 * (2 * wv + c) + l15) * 4 + q];
        }

        // int8 matvec: 6 gh-tiles per wave. A-frag A[m=l15][k=16q+j] shared.
        i32x4 acc[2][3];
        #pragma unroll
        for (int c = 0; c < 2; ++c)
            #pragma unroll
            for (int s = 0; s < 3; ++s) acc[c][s] = (i32x4){0, 0, 0, 0};
        #pragma unroll
        for (int kk = 0; kk < 4; ++kk) {
            const i32x4 a = *(const i32x4*)(&hbuf[pb][l15][kk * 64 + q * 16]);
            #pragma unroll
            for (int c = 0; c < 2; ++c) {
                acc[c][0] = __builtin_amdgcn_mfma_i32_16x16x64_i8(a, W[c][0][kk], acc[c][0], 0, 0, 0);
                acc[c][1] = __builtin_amdgcn_mfma_i32_16x16x64_i8(a, W[c][1][kk], acc[c][1], 0, 0, 0);
                acc[c][2] = __builtin_amdgcn_mfma_i32_16x16x64_i8(a, W[c][2][kk], acc[c][2], 0, 0, 0);
            }
        }

        // Lane-pack: C-frag valid rows 0..3 live in lanes 0..15, reg==row.
        // Build so lane (q,l15) holds (row q, col l15):
        //   x01 = {r0 @ lanes 0-15, r1 @ lanes 16-31, ...}
        //   x23 = {r2 @ lanes 0-15, r3 @ lanes 16-31, ...}
        //   merge lower halves: lanes 0-31 <- x01, lanes 32-63 <- x23[0:32].
        float P[2][3];
        #pragma unroll
        for (int c = 0; c < 2; ++c)
            #pragma unroll
            for (int s = 0; s < 3; ++s) {
                const int r1b = __shfl(acc[c][s][1], l15, 64);
                const int r3b = __shfl(acc[c][s][3], l15, 64);
                const int x01 = (lane < 16) ? acc[c][s][0] : r1b;
                const int x23 = (lane < 16) ? acc[c][s][2] : r3b;
                P[c][s] = (float)lane32_merge(x01, x23);
            }

        float* outt = out + ((size_t)t * NB + wg * 4 + q) * CDIM;
        const int pbn = pb ^ 1;
        #pragma unroll
        for (int c = 0; c < 2; ++c) {
            const int jc = 32 * wv + 16 * c + l15;        // owned h column
            const float a_r = fmaf(d[c][0], P[c][0], bf2f(xc[c][0]) + bh[c][0]);
            const float rg  = __builtin_amdgcn_rcpf(
                1.f + __builtin_amdgcn_exp2f(-LOG2E * a_r));
            const float a_z = fmaf(d[c][1], P[c][1], bf2f(xc[c][1]) + bh[c][1]);
            const float ez  = __builtin_amdgcn_exp2f(-LOG2E * a_z);
            const float zi  = __builtin_amdgcn_rcpf(1.f + ez);     // = z
            const float hng = fmaf(d[c][2], P[c][2], bh[c][2]);
            const float na  = fmaf(rg, hng, bf2f(xc[c][2]));
            const float e2  = __builtin_amdgcn_exp2f(2.f * LOG2E * na);
            const float th  = 1.f - 2.f * __builtin_amdgcn_rcpf(e2 + 1.f);  // tanh
            const float hv  = zi * fmaf(ez, th, h[c]);             // (1-z)n + zh
            h[c] = hv;
            hbuf[pbn][q][jc] = (signed char)(int)rintf(hv * 127.f);
            outt[jc] = hv;
        }
        // lgkm-only barrier: publish hbuf[pbn]; skip vmcnt(0) drain (out
        // stores + xp prefetch are lane-private, no cross-wave global deps)
        asm volatile("s_waitcnt lgkmcnt(0)\n\ts_barrier" ::: "memory");
        pb = pbn;
        #pragma unroll
        for (int c = 0; c < 2; ++c)
            #pragma unroll
            for (int s = 0; s < 3; ++s) xc[c][s] = xn_[c][s];
    }
}

// ---------------------------------------------------------------------------
// K3: in-place log_softmax over C=256. One wave per row, 4 rows per block.
// ---------------------------------------------------------------------------
__global__ __launch_bounds__(256) void logsoftmax_rows(float* __restrict__ out)
{
    const int tid  = threadIdx.x;
    const int wv   = tid >> 6, lane = tid & 63;
    const int row  = blockIdx.x * 4 + wv;     // 0..63999
    float* p = out + (size_t)row * CDIM + lane * 4;
    float4 v = *(const float4*)p;

    float m = fmaxf(fmaxf(v.x, v.y), fmaxf(v.z, v.w));
    #pragma unroll
    for (int s = 32; s > 0; s >>= 1) m = fmaxf(m, __shfl_xor(m, s, 64));

    float sum = __builtin_amdgcn_exp2f((v.x - m) * LOG2E)
              + __builtin_amdgcn_exp2f((v.y - m) * LOG2E)
              + __builtin_amdgcn_exp2f((v.z - m) * LOG2E)
              + __builtin_amdgcn_exp2f((v.w - m) * LOG2E);
    #pragma unroll
    for (int s = 32; s > 0; s >>= 1) sum += __shfl_xor(sum, s, 64);

    const float lse = m + __builtin_amdgcn_logf(sum) * 0.69314718055994531f;
    v.x -= lse; v.y -= lse; v.z -= lse; v.w -= lse;
    *(float4*)p = v;
}

// ---------------------------------------------------------------------------
// Workspace layout (bytes):
//   xp2     @ 0           : 1000*768*64*2 = 98,304,000
//   wih_bf  @ 98,304,000  : 786,432*2     =  1,572,864
//   whhq    @ 99,876,864  : 196,608       =    196,608
//   dscale  @ 100,073,472 : 768*4         =      3,072
// ---------------------------------------------------------------------------
extern "C" void kernel_launch(void* const* d_in, const int* in_sizes, int n_in,
                              void* d_out, int out_size, void* d_ws, size_t ws_size,
                              hipStream_t stream)
{
    const float* enc = (const float*)d_in[0];   // [1000,64,1024]
    const float* wih = (const float*)d_in[1];   // [768,1024]
    const float* whh = (const float*)d_in[2];   // [768,256]
    const float* bih = (const float*)d_in[3];   // [768]
    const float* bhh = (const float*)d_in[4];   // [768]
    float* out = (float*)d_out;                 // [1000,64,256]

    unsigned short* xp2    = (unsigned short*)d_ws;
    unsigned short* wih_bf = (unsigned short*)((char*)d_ws + 98304000);
    signed char*    whhq   = (signed char*)((char*)d_ws + 99876864);
    float*          dsc    = (float*)((char*)d_ws + 100073472);

    cvt_wih<<<dim3(3072), dim3(256), 0, stream>>>(wih, wih_bf);
    quant_whh<<<dim3(768), dim3(64), 0, stream>>>(whh, whhq, dsc);
    xproj_gemm<<<dim3(12, 1000), dim3(256), 0, stream>>>(enc, wih_bf, bih, xp2);
    gru_scan<<<dim3(16), dim3(512), 0, stream>>>(xp2, whhq, dsc, bhh, out);
    logsoftmax_rows<<<dim3(16000), dim3(256), 0, stream>>>(out);
}

// Round 3
// 1470.047 us; speedup vs baseline: 1.3769x; 1.0737x over previous
//
#include <hip/hip_runtime.h>
#include <stdint.h>

// Problem constants (reference: T=1000, N=64, H=1024, C=256)
#define T_STEPS 1000
#define NB      64
#define HDIM    1024
#define CDIM    256
#define G3      768          // 3*C
#define LOG2E   1.44269504088896340736f

typedef float f32x4  __attribute__((ext_vector_type(4)));
typedef short bf16x8 __attribute__((ext_vector_type(8)));   // 8 bf16 in 4 VGPRs
typedef int   i32x4  __attribute__((ext_vector_type(4)));   // 16 int8 in 4 VGPRs

__device__ __forceinline__ float bf2f(unsigned short u) {
    union { unsigned int i; float f; } v; v.i = ((unsigned int)u) << 16; return v.f;
}
__device__ __forceinline__ unsigned short f2bf(float f) {
    union { float f; unsigned int i; } v; v.f = f;
    unsigned int r = v.i + 0x7fffu + ((v.i >> 16) & 1u);   // RNE
    return (unsigned short)(r >> 16);
}

// Pack MFMA C-frag rows 0..3 (valid data: lanes 0-15, regs 0-3) so that
// result lane 16*r + l15 holds reg r of lane l15.  Pure cross-lane VALU:
//   y01 = permlane16_swap(a0,a1) -> lanes 0-15 = a0[0:16], 16-31 = a1[0:16]
//   y23 = permlane16_swap(a2,a3) -> lanes 0-15 = a2[0:16], 16-31 = a3[0:16]
//   P   = permlane32_swap(y01,y23) -> lanes 0-31 = y01, 32-63 = y23[0:32]
__device__ __forceinline__ int pack4(i32x4 a) {
#if __has_builtin(__builtin_amdgcn_permlane16_swap) && __has_builtin(__builtin_amdgcn_permlane32_swap)
    auto y01 = __builtin_amdgcn_permlane16_swap(a[0], a[1], false, false);
    auto y23 = __builtin_amdgcn_permlane16_swap(a[2], a[3], false, false);
    auto p   = __builtin_amdgcn_permlane32_swap(y01[0], y23[0], false, false);
    return p[0];
#else
    const int lane = threadIdx.x & 63;
    const int l15  = lane & 15;
    const int r1b = __shfl(a[1], l15, 64);
    const int r3b = __shfl(a[3], l15, 64);
    const int x01 = (lane < 16) ? a[0] : r1b;
    const int x23 = (lane < 16) ? a[2] : r3b;
    const int lo  = __shfl(x23, lane & 31, 64);
    return (lane < 32) ? x01 : lo;
#endif
}

// ---------------------------------------------------------------------------
// K0: convert W_ih [768,1024] fp32 -> bf16
// ---------------------------------------------------------------------------
__global__ __launch_bounds__(256) void cvt_wih(
    const float* __restrict__ wih, unsigned short* __restrict__ wih_bf)
{
    int idx = blockIdx.x * 256 + threadIdx.x;          // grid covers exactly 786432
    wih_bf[idx] = f2bf(wih[idx]);
}

// ---------------------------------------------------------------------------
// K0b: per-row symmetric int8 quantization of W_hh [768,256].
// ---------------------------------------------------------------------------
__global__ __launch_bounds__(64) void quant_whh(
    const float* __restrict__ whh, signed char* __restrict__ wq,
    float* __restrict__ dscale)
{
    const int g    = blockIdx.x;          // 0..767
    const int lane = threadIdx.x;         // 0..63
    const float4 w = *(const float4*)(whh + (size_t)g * CDIM + lane * 4);
    float m = fmaxf(fmaxf(fabsf(w.x), fabsf(w.y)), fmaxf(fabsf(w.z), fabsf(w.w)));
    #pragma unroll
    for (int s = 32; s > 0; s >>= 1) m = fmaxf(m, __shfl_xor(m, s, 64));
    const float inv = (m > 0.f) ? 127.f / m : 0.f;
    char4 q;
    q.x = (signed char)(int)rintf(w.x * inv);
    q.y = (signed char)(int)rintf(w.y * inv);
    q.z = (signed char)(int)rintf(w.z * inv);
    q.w = (signed char)(int)rintf(w.w * inv);
    *(char4*)(wq + (size_t)g * CDIM + lane * 4) = q;
    if (lane == 0) dscale[g] = m / (127.f * 127.f);
}

// ---------------------------------------------------------------------------
// K1: xp2[t][wgslab][g][n4] (bf16) = enc[t,4*wgslab+n4,:] . W_ih[g,:] + b_ih[g]
// 16-slab layout (4 batch rows per scan-WG). 256 thr, M=64,G=64,BK=64.
// ---------------------------------------------------------------------------
__global__ __launch_bounds__(256) void xproj_gemm(
    const float* __restrict__ enc,            // [64000,1024] fp32
    const unsigned short* __restrict__ wih,   // [768,1024] bf16
    const float* __restrict__ bih,            // [768] fp32
    unsigned short* __restrict__ xp2)         // [1000][16][768][4] bf16
{
    const int gt_base = blockIdx.x * 64;      // G-tile base (12 tiles)
    const int t       = blockIdx.y;           // M-tile == timestep (1000)
    const int tid  = threadIdx.x;
    const int w    = tid >> 6;                // wave 0..3 -> M rows [16w,16w+16)
    const int lane = tid & 63;
    const int q    = lane >> 4, l15 = lane & 15;

    __shared__ unsigned short As[64][72];
    __shared__ unsigned short Bs[64][72];

    const f32x4 zero4 = {0.f, 0.f, 0.f, 0.f};
    f32x4 acc[4] = {zero4, zero4, zero4, zero4};

    const int arow = tid >> 4;                // 0..15
    const int acol = (tid & 15) * 4;          // 0..60
    const int brow = tid >> 3;                // 0..31
    const int bcol = (tid & 7) * 8;           // 0..56

    for (int kt = 0; kt < 16; ++kt) {
        const int k0 = kt * 64;
        __syncthreads();
        #pragma unroll
        for (int i = 0; i < 4; ++i) {
            const int r = arow + i * 16;
            const float4 av = *(const float4*)(enc + (size_t)(t * 64 + r) * HDIM + k0 + acol);
            ushort4 u;
            u.x = f2bf(av.x); u.y = f2bf(av.y); u.z = f2bf(av.z); u.w = f2bf(av.w);
            *(ushort4*)(&As[r][acol]) = u;
        }
        #pragma unroll
        for (int i = 0; i < 2; ++i) {
            const int r = brow + i * 32;
            const uint4 bv = *(const uint4*)(wih + (size_t)(gt_base + r) * HDIM + k0 + bcol);
            *(uint4*)(&Bs[r][bcol]) = bv;
        }
        __syncthreads();
        #pragma unroll
        for (int kk = 0; kk < 2; ++kk) {
            const bf16x8 a = *(const bf16x8*)(&As[16 * w + l15][kk * 32 + q * 8]);
            #pragma unroll
            for (int g = 0; g < 4; ++g) {
                const bf16x8 b = *(const bf16x8*)(&Bs[16 * g + l15][kk * 32 + q * 8]);
                acc[g] = __builtin_amdgcn_mfma_f32_16x16x32_bf16(a, b, acc[g], 0, 0, 0);
            }
        }
    }

    // C row = 16w + 4q + r  ->  slab = 4w+q, subrow = r. ushort4 contiguous.
    #pragma unroll
    for (int g = 0; g < 4; ++g) {
        const int gg = gt_base + 16 * g + l15;
        const float bias = bih[gg];
        ushort4 u;
        u.x = f2bf(acc[g][0] + bias);
        u.y = f2bf(acc[g][1] + bias);
        u.z = f2bf(acc[g][2] + bias);
        u.w = f2bf(acc[g][3] + bias);
        *(ushort4*)(xp2 + ((size_t)((t * 16 + 4 * w + q) * G3 + gg)) * 4) = u;
    }
}

// ---------------------------------------------------------------------------
// K2: persistent GRU scan, int8 recurrent matvec.
// 16 WGs x 1024 thr (16 waves = 4 waves/SIMD for overlap). WG wg owns batch
// rows [4wg, 4wg+4). MFMA M=16 padded (hbuf rows 4..15 stay zero).
// Wave wv owns ONE h col-tile (cols 16wv..16wv+15) x 3 gates:
//   per wave: 12 MFMA (3 gate-tiles x 4 K-steps), 3 lane-packs, 1 gate elem
//   per lane. Per-SIMD totals (48 MFMA, gate VALU) are unchanged vs the
//   8-wave config -- the win is 4-deep wave overlap per SIMD.
// Lane-pack is now pure VALU (2x permlane16_swap + permlane32_swap), removing
// all ds_bpermute traffic from the LDS pipe. W_hh int8 register-resident
// (48 VGPR, pinned). h int8 in LDS, double-buffered; ONE lgkm-only barrier
// per step; xp prefetched 1 step ahead.
// ---------------------------------------------------------------------------
__global__ void __launch_bounds__(1024)
__attribute__((amdgpu_waves_per_eu(4, 4)))
gru_scan(
    const unsigned short* __restrict__ xp2,   // [1000][16][768][4] bf16
    const signed char* __restrict__ wq,       // [768][256] int8
    const float* __restrict__ dscale,         // [768] fp32
    const float* __restrict__ bhh,            // [768] fp32
    float* __restrict__ out)                  // [64000][256] fp32 (pre-softmax)
{
    const int wg   = blockIdx.x;              // 0..15
    const int tid  = threadIdx.x;
    const int wv   = tid >> 6;                // 0..15
    const int lane = tid & 63;
    const int q    = lane >> 4, l15 = lane & 15;
    const int jc   = 16 * wv + l15;           // owned h column 0..255

    // row stride 304 B (19*16): 16B-aligned rows, start-bank spread for b128
    __shared__ __align__(16) signed char hbuf[2][16][304];

    // Preload int8 W fragments. B-frag for 16x16x64 i8: B[n=l15][k=16q+j].
    i32x4 W[3][4];
    float d[3], bh[3];
    #pragma unroll
    for (int s = 0; s < 3; ++s) {
        const int g = 256 * s + jc;
        d[s]  = dscale[g];
        bh[s] = bhh[g];
        #pragma unroll
        for (int kk = 0; kk < 4; ++kk)
            W[s][kk] = *(const i32x4*)(wq + (size_t)g * CDIM + kk * 64 + q * 16);
    }
    #pragma unroll
    for (int s = 0; s < 3; ++s)
        asm volatile("" : "+v"(W[s][0]), "+v"(W[s][1]),
                          "+v"(W[s][2]), "+v"(W[s][3]));

    float h = 0.f;                            // h for (row q, col jc)

    for (int i = tid; i < 2 * 16 * 304; i += 1024) ((signed char*)hbuf)[i] = 0;
    __syncthreads();

    // xp prefetch for t=0: 3 scalar bf16 elements per lane
    unsigned short xc[3];
    {
        const unsigned short* xpt = xp2 + (size_t)wg * (G3 * 4);
        #pragma unroll
        for (int s = 0; s < 3; ++s)
            xc[s] = xpt[(256 * s + jc) * 4 + q];
    }

    int pb = 0;
    for (int t = 0; t < T_STEPS; ++t) {
        // prefetch xp for t+1 (latency hides under MFMA + gate phase)
        const int tn = (t + 1 < T_STEPS) ? t + 1 : t;
        unsigned short xn_[3];
        {
            const unsigned short* xpt = xp2 + ((size_t)tn * 16 + wg) * (G3 * 4);
            #pragma unroll
            for (int s = 0; s < 3; ++s)
                xn_[s] = xpt[(256 * s + jc) * 4 + q];
        }

        // int8 matvec: 3 gh-tiles per wave. A-frag A[m=l15][k=16q+j] shared.
        i32x4 acc[3];
        #pragma unroll
        for (int s = 0; s < 3; ++s) acc[s] = (i32x4){0, 0, 0, 0};
        #pragma unroll
        for (int kk = 0; kk < 4; ++kk) {
            const i32x4 a = *(const i32x4*)(&hbuf[pb][l15][kk * 64 + q * 16]);
            acc[0] = __builtin_amdgcn_mfma_i32_16x16x64_i8(a, W[0][kk], acc[0], 0, 0, 0);
            acc[1] = __builtin_amdgcn_mfma_i32_16x16x64_i8(a, W[1][kk], acc[1], 0, 0, 0);
            acc[2] = __builtin_amdgcn_mfma_i32_16x16x64_i8(a, W[2][kk], acc[2], 0, 0, 0);
        }

        // Lane-pack: pure-VALU permlane; lane (q,l15) <- (row q, col l15).
        float P[3];
        #pragma unroll
        for (int s = 0; s < 3; ++s) P[s] = (float)pack4(acc[s]);

        const int pbn = pb ^ 1;
        {
            const float a_r = fmaf(d[0], P[0], bf2f(xc[0]) + bh[0]);
            const float rg  = __builtin_amdgcn_rcpf(
                1.f + __builtin_amdgcn_exp2f(-LOG2E * a_r));
            const float a_z = fmaf(d[1], P[1], bf2f(xc[1]) + bh[1]);
            const float ez  = __builtin_amdgcn_exp2f(-LOG2E * a_z);
            const float zi  = __builtin_amdgcn_rcpf(1.f + ez);     // = z
            const float hng = fmaf(d[2], P[2], bh[2]);
            const float na  = fmaf(rg, hng, bf2f(xc[2]));
            const float e2  = __builtin_amdgcn_exp2f(2.f * LOG2E * na);
            const float th  = 1.f - 2.f * __builtin_amdgcn_rcpf(e2 + 1.f);  // tanh
            const float hv  = zi * fmaf(ez, th, h);                // (1-z)n + zh
            h = hv;
            hbuf[pbn][q][jc] = (signed char)(int)rintf(hv * 127.f);
            out[((size_t)t * NB + wg * 4 + q) * CDIM + jc] = hv;
        }
        // lgkm-only barrier: publish hbuf[pbn]; skip vmcnt(0) drain (out
        // stores + xp prefetch are lane-private, no cross-wave global deps)
        asm volatile("s_waitcnt lgkmcnt(0)\n\ts_barrier" ::: "memory");
        pb = pbn;
        #pragma unroll
        for (int s = 0; s < 3; ++s) xc[s] = xn_[s];
    }
}

// ---------------------------------------------------------------------------
// K3: in-place log_softmax over C=256. One wave per row, 4 rows per block.
// ---------------------------------------------------------------------------
__global__ __launch_bounds__(256) void logsoftmax_rows(float* __restrict__ out)
{
    const int tid  = threadIdx.x;
    const int wv   = tid >> 6, lane = tid & 63;
    const int row  = blockIdx.x * 4 + wv;     // 0..63999
    float* p = out + (size_t)row * CDIM + lane * 4;
    float4 v = *(const float4*)p;

    float m = fmaxf(fmaxf(v.x, v.y), fmaxf(v.z, v.w));
    #pragma unroll
    for (int s = 32; s > 0; s >>= 1) m = fmaxf(m, __shfl_xor(m, s, 64));

    float sum = __builtin_amdgcn_exp2f((v.x - m) * LOG2E)
              + __builtin_amdgcn_exp2f((v.y - m) * LOG2E)
              + __builtin_amdgcn_exp2f((v.z - m) * LOG2E)
              + __builtin_amdgcn_exp2f((v.w - m) * LOG2E);
    #pragma unroll
    for (int s = 32; s > 0; s >>= 1) sum += __shfl_xor(sum, s, 64);

    const float lse = m + __builtin_amdgcn_logf(sum) * 0.69314718055994531f;
    v.x -= lse; v.y -= lse; v.z -= lse; v.w -= lse;
    *(float4*)p = v;
}

// ---------------------------------------------------------------------------
// Workspace layout (bytes):
//   xp2     @ 0           : 1000*768*64*2 = 98,304,000
//   wih_bf  @ 98,304,000  : 786,432*2     =  1,572,864
//   whhq    @ 99,876,864  : 196,608       =    196,608
//   dscale  @ 100,073,472 : 768*4         =      3,072
// ---------------------------------------------------------------------------
extern "C" void kernel_launch(void* const* d_in, const int* in_sizes, int n_in,
                              void* d_out, int out_size, void* d_ws, size_t ws_size,
                              hipStream_t stream)
{
    const float* enc = (const float*)d_in[0];   // [1000,64,1024]
    const float* wih = (const float*)d_in[1];   // [768,1024]
    const float* whh = (const float*)d_in[2];   // [768,256]
    const float* bih = (const float*)d_in[3];   // [768]
    const float* bhh = (const float*)d_in[4];   // [768]
    float* out = (float*)d_out;                 // [1000,64,256]

    unsigned short* xp2    = (unsigned short*)d_ws;
    unsigned short* wih_bf = (unsigned short*)((char*)d_ws + 98304000);
    signed char*    whhq   = (signed char*)((char*)d_ws + 99876864);
    float*          dsc    = (float*)((char*)d_ws + 100073472);

    cvt_wih<<<dim3(3072), dim3(256), 0, stream>>>(wih, wih_bf);
    quant_whh<<<dim3(768), dim3(64), 0, stream>>>(whh, whhq, dsc);
    xproj_gemm<<<dim3(12, 1000), dim3(256), 0, stream>>>(enc, wih_bf, bih, xp2);
    gru_scan<<<dim3(16), dim3(1024), 0, stream>>>(xp2, whhq, dsc, bhh, out);
    logsoftmax_rows<<<dim3(16000), dim3(256), 0, stream>>>(out);
}

// Round 4
// 1419.392 us; speedup vs baseline: 1.4261x; 1.0357x over previous
//
#include <hip/hip_runtime.h>
#include <stdint.h>

// Problem constants (reference: T=1000, N=64, H=1024, C=256)
#define T_STEPS 1000
#define NB      64
#define HDIM    1024
#define CDIM    256
#define G3      768          // 3*C
#define LOG2E   1.44269504088896340736f

typedef float f32x4  __attribute__((ext_vector_type(4)));
typedef short bf16x8 __attribute__((ext_vector_type(8)));   // 8 bf16 in 4 VGPRs
typedef int   i32x4  __attribute__((ext_vector_type(4)));   // 16 int8 in 4 VGPRs

__device__ __forceinline__ float bf2f(unsigned short u) {
    union { unsigned int i; float f; } v; v.i = ((unsigned int)u) << 16; return v.f;
}
__device__ __forceinline__ unsigned short f2bf(float f) {
    union { float f; unsigned int i; } v; v.f = f;
    unsigned int r = v.i + 0x7fffu + ((v.i >> 16) & 1u);   // RNE
    return (unsigned short)(r >> 16);
}

// Pack MFMA C-frag rows 0..3 (valid data: lanes 0-15, regs 0-3) so that
// result lane 16*r + l15 holds reg r of lane l15.  Pure cross-lane VALU.
__device__ __forceinline__ int pack4(i32x4 a) {
#if __has_builtin(__builtin_amdgcn_permlane16_swap) && __has_builtin(__builtin_amdgcn_permlane32_swap)
    auto y01 = __builtin_amdgcn_permlane16_swap(a[0], a[1], false, false);
    auto y23 = __builtin_amdgcn_permlane16_swap(a[2], a[3], false, false);
    auto p   = __builtin_amdgcn_permlane32_swap(y01[0], y23[0], false, false);
    return p[0];
#else
    const int lane = threadIdx.x & 63;
    const int l15  = lane & 15;
    const int r1b = __shfl(a[1], l15, 64);
    const int r3b = __shfl(a[3], l15, 64);
    const int x01 = (lane < 16) ? a[0] : r1b;
    const int x23 = (lane < 16) ? a[2] : r3b;
    const int lo  = __shfl(x23, lane & 31, 64);
    return (lane < 32) ? x01 : lo;
#endif
}

// ---------------------------------------------------------------------------
// K0: convert W_ih [768,1024] fp32 -> bf16
// ---------------------------------------------------------------------------
__global__ __launch_bounds__(256) void cvt_wih(
    const float* __restrict__ wih, unsigned short* __restrict__ wih_bf)
{
    int idx = blockIdx.x * 256 + threadIdx.x;          // grid covers exactly 786432
    wih_bf[idx] = f2bf(wih[idx]);
}

// ---------------------------------------------------------------------------
// K0c: convert encoder_output [64000,1024] fp32 -> bf16 (once; kills the 12x
// per-G-tile cvt redundancy inside the projection GEMM).
// ---------------------------------------------------------------------------
__global__ __launch_bounds__(256) void cvt_enc(
    const float* __restrict__ e, unsigned short* __restrict__ eb)
{
    const size_t i = ((size_t)blockIdx.x * 256 + threadIdx.x) * 8;
    const float4 v0 = *(const float4*)(e + i);
    const float4 v1 = *(const float4*)(e + i + 4);
    ushort4 u0, u1;
    u0.x = f2bf(v0.x); u0.y = f2bf(v0.y); u0.z = f2bf(v0.z); u0.w = f2bf(v0.w);
    u1.x = f2bf(v1.x); u1.y = f2bf(v1.y); u1.z = f2bf(v1.z); u1.w = f2bf(v1.w);
    *(ushort4*)(eb + i)     = u0;
    *(ushort4*)(eb + i + 4) = u1;
}

// ---------------------------------------------------------------------------
// K0b: per-row symmetric int8 quantization of W_hh [768,256].
// ---------------------------------------------------------------------------
__global__ __launch_bounds__(64) void quant_whh(
    const float* __restrict__ whh, signed char* __restrict__ wq,
    float* __restrict__ dscale)
{
    const int g    = blockIdx.x;          // 0..767
    const int lane = threadIdx.x;         // 0..63
    const float4 w = *(const float4*)(whh + (size_t)g * CDIM + lane * 4);
    float m = fmaxf(fmaxf(fabsf(w.x), fabsf(w.y)), fmaxf(fabsf(w.z), fabsf(w.w)));
    #pragma unroll
    for (int s = 32; s > 0; s >>= 1) m = fmaxf(m, __shfl_xor(m, s, 64));
    const float inv = (m > 0.f) ? 127.f / m : 0.f;
    char4 q;
    q.x = (signed char)(int)rintf(w.x * inv);
    q.y = (signed char)(int)rintf(w.y * inv);
    q.z = (signed char)(int)rintf(w.z * inv);
    q.w = (signed char)(int)rintf(w.w * inv);
    *(char4*)(wq + (size_t)g * CDIM + lane * 4) = q;
    if (lane == 0) dscale[g] = m / (127.f * 127.f);
}

// ---------------------------------------------------------------------------
// K1 (fallback, known-good): xp2 = enc . W_ih^T + b_ih with in-loop fp32->bf16
// cvt of A. Used only if workspace is too small for enc_bf.
// ---------------------------------------------------------------------------
__global__ __launch_bounds__(256) void xproj_gemm(
    const float* __restrict__ enc,            // [64000,1024] fp32
    const unsigned short* __restrict__ wih,   // [768,1024] bf16
    const float* __restrict__ bih,            // [768] fp32
    unsigned short* __restrict__ xp2)         // [1000][16][768][4] bf16
{
    const int gt_base = blockIdx.x * 64;      // G-tile base (12 tiles)
    const int t       = blockIdx.y;           // M-tile == timestep (1000)
    const int tid  = threadIdx.x;
    const int w    = tid >> 6;                // wave 0..3 -> M rows [16w,16w+16)
    const int lane = tid & 63;
    const int q    = lane >> 4, l15 = lane & 15;

    __shared__ unsigned short As[64][72];
    __shared__ unsigned short Bs[64][72];

    const f32x4 zero4 = {0.f, 0.f, 0.f, 0.f};
    f32x4 acc[4] = {zero4, zero4, zero4, zero4};

    const int arow = tid >> 4;                // 0..15
    const int acol = (tid & 15) * 4;          // 0..60
    const int brow = tid >> 3;                // 0..31
    const int bcol = (tid & 7) * 8;           // 0..56

    for (int kt = 0; kt < 16; ++kt) {
        const int k0 = kt * 64;
        __syncthreads();
        #pragma unroll
        for (int i = 0; i < 4; ++i) {
            const int r = arow + i * 16;
            const float4 av = *(const float4*)(enc + (size_t)(t * 64 + r) * HDIM + k0 + acol);
            ushort4 u;
            u.x = f2bf(av.x); u.y = f2bf(av.y); u.z = f2bf(av.z); u.w = f2bf(av.w);
            *(ushort4*)(&As[r][acol]) = u;
        }
        #pragma unroll
        for (int i = 0; i < 2; ++i) {
            const int r = brow + i * 32;
            const uint4 bv = *(const uint4*)(wih + (size_t)(gt_base + r) * HDIM + k0 + bcol);
            *(uint4*)(&Bs[r][bcol]) = bv;
        }
        __syncthreads();
        #pragma unroll
        for (int kk = 0; kk < 2; ++kk) {
            const bf16x8 a = *(const bf16x8*)(&As[16 * w + l15][kk * 32 + q * 8]);
            #pragma unroll
            for (int g = 0; g < 4; ++g) {
                const bf16x8 b = *(const bf16x8*)(&Bs[16 * g + l15][kk * 32 + q * 8]);
                acc[g] = __builtin_amdgcn_mfma_f32_16x16x32_bf16(a, b, acc[g], 0, 0, 0);
            }
        }
    }

    #pragma unroll
    for (int g = 0; g < 4; ++g) {
        const int gg = gt_base + 16 * g + l15;
        const float bias = bih[gg];
        ushort4 u;
        u.x = f2bf(acc[g][0] + bias);
        u.y = f2bf(acc[g][1] + bias);
        u.z = f2bf(acc[g][2] + bias);
        u.w = f2bf(acc[g][3] + bias);
        *(ushort4*)(xp2 + ((size_t)((t * 16 + 4 * w + q) * G3 + gg)) * 4) = u;
    }
}

// ---------------------------------------------------------------------------
// K1' (primary): bf16-A variant. A staged as raw uint4 (no cvt), global loads
// for kt+1 register-prefetched under the MFMA phase of kt (T14 split).
// ---------------------------------------------------------------------------
__global__ __launch_bounds__(256) void xproj_gemm_bf(
    const unsigned short* __restrict__ encb,  // [64000,1024] bf16
    const unsigned short* __restrict__ wih,   // [768,1024] bf16
    const float* __restrict__ bih,            // [768] fp32
    unsigned short* __restrict__ xp2)         // [1000][16][768][4] bf16
{
    const int gt_base = blockIdx.x * 64;      // G-tile base (12 tiles)
    const int t       = blockIdx.y;           // M-tile == timestep (1000)
    const int tid  = threadIdx.x;
    const int w    = tid >> 6;                // wave 0..3 -> M rows [16w,16w+16)
    const int lane = tid & 63;
    const int q    = lane >> 4, l15 = lane & 15;

    __shared__ unsigned short As[64][72];
    __shared__ unsigned short Bs[64][72];

    const f32x4 zero4 = {0.f, 0.f, 0.f, 0.f};
    f32x4 acc[4] = {zero4, zero4, zero4, zero4};

    const int srow = tid >> 3;                // 0..31
    const int scol = (tid & 7) * 8;           // 0..56

    const unsigned short* aptr = encb + (size_t)(t * 64 + srow) * HDIM + scol;
    const unsigned short* bptr = wih  + (size_t)(gt_base + srow) * HDIM + scol;

    // prefetch kt=0
    uint4 a0 = *(const uint4*)(aptr);
    uint4 a1 = *(const uint4*)(aptr + 32 * HDIM);
    uint4 b0 = *(const uint4*)(bptr);
    uint4 b1 = *(const uint4*)(bptr + 32 * HDIM);

    for (int kt = 0; kt < 16; ++kt) {
        __syncthreads();                       // prev MFMA done with LDS
        *(uint4*)(&As[srow][scol])      = a0;
        *(uint4*)(&As[srow + 32][scol]) = a1;
        *(uint4*)(&Bs[srow][scol])      = b0;
        *(uint4*)(&Bs[srow + 32][scol]) = b1;
        __syncthreads();                       // LDS[kt] ready
        if (kt + 1 < 16) {                     // latency hides under MFMA
            const int k0n = (kt + 1) * 64;
            a0 = *(const uint4*)(aptr + k0n);
            a1 = *(const uint4*)(aptr + 32 * HDIM + k0n);
            b0 = *(const uint4*)(bptr + k0n);
            b1 = *(const uint4*)(bptr + 32 * HDIM + k0n);
        }
        #pragma unroll
        for (int kk = 0; kk < 2; ++kk) {
            const bf16x8 a = *(const bf16x8*)(&As[16 * w + l15][kk * 32 + q * 8]);
            #pragma unroll
            for (int g = 0; g < 4; ++g) {
                const bf16x8 b = *(const bf16x8*)(&Bs[16 * g + l15][kk * 32 + q * 8]);
                acc[g] = __builtin_amdgcn_mfma_f32_16x16x32_bf16(a, b, acc[g], 0, 0, 0);
            }
        }
    }

    // C row = 16w + 4q + r  ->  slab = 4w+q, subrow = r. ushort4 contiguous.
    #pragma unroll
    for (int g = 0; g < 4; ++g) {
        const int gg = gt_base + 16 * g + l15;
        const float bias = bih[gg];
        ushort4 u;
        u.x = f2bf(acc[g][0] + bias);
        u.y = f2bf(acc[g][1] + bias);
        u.z = f2bf(acc[g][2] + bias);
        u.w = f2bf(acc[g][3] + bias);
        *(ushort4*)(xp2 + ((size_t)((t * 16 + 4 * w + q) * G3 + gg)) * 4) = u;
    }
}

// ---------------------------------------------------------------------------
// K2: persistent GRU scan, int8 recurrent matvec.
// 16 WGs x 1024 thr (4 waves/SIMD). WG wg owns batch rows [4wg, 4wg+4).
// MFMA M=16 padded; only rows 0-3 of hbuf are valid. A-frag ds_read_b128 is
// EXEC-MASKED to lanes l15<4 (16 lanes): garbage A rows 4-15 would only feed
// C rows 4-15, which the lane-pack never reads -- so we read 1KB/wave/step
// instead of 4KB. Persistent Areg[] zero-init once keeps inactive lanes 0.
// hbuf row stride 320B (80 dw === 16 mod 32): the 16-lane b128 read maps
// exactly 2 lanes/bank (free). Accumulators split into 2 K-chains (6
// independent MFMA chains, dep distance 6) to cover MFMA latency.
// W_hh int8 register-resident (48 VGPR, pinned). h int8 in LDS, dbuf;
// ONE lgkm-only barrier per step; xp prefetched 1 step ahead.
// ---------------------------------------------------------------------------
__global__ void __launch_bounds__(1024)
__attribute__((amdgpu_waves_per_eu(4, 4)))
gru_scan(
    const unsigned short* __restrict__ xp2,   // [1000][16][768][4] bf16
    const signed char* __restrict__ wq,       // [768][256] int8
    const float* __restrict__ dscale,         // [768] fp32
    const float* __restrict__ bhh,            // [768] fp32
    float* __restrict__ out)                  // [64000][256] fp32 (pre-softmax)
{
    const int wg   = blockIdx.x;              // 0..15
    const int tid  = threadIdx.x;
    const int wv   = tid >> 6;                // 0..15
    const int lane = tid & 63;
    const int q    = lane >> 4, l15 = lane & 15;
    const int jc   = 16 * wv + l15;           // owned h column 0..255

    __shared__ __align__(16) signed char hbuf[2][16][320];

    // Preload int8 W fragments. B-frag for 16x16x64 i8: B[n=l15][k=16q+j].
    i32x4 W[3][4];
    float d[3], bh[3];
    #pragma unroll
    for (int s = 0; s < 3; ++s) {
        const int g = 256 * s + jc;
        d[s]  = dscale[g];
        bh[s] = bhh[g];
        #pragma unroll
        for (int kk = 0; kk < 4; ++kk)
            W[s][kk] = *(const i32x4*)(wq + (size_t)g * CDIM + kk * 64 + q * 16);
    }
    #pragma unroll
    for (int s = 0; s < 3; ++s)
        asm volatile("" : "+v"(W[s][0]), "+v"(W[s][1]),
                          "+v"(W[s][2]), "+v"(W[s][3]));

    float h = 0.f;                            // h for (row q, col jc)

    for (int i = tid; i < 2 * 16 * 320; i += 1024) ((signed char*)hbuf)[i] = 0;
    __syncthreads();

    // xp prefetch for t=0: 3 scalar bf16 elements per lane
    unsigned short xc[3];
    {
        const unsigned short* xpt = xp2 + (size_t)wg * (G3 * 4);
        #pragma unroll
        for (int s = 0; s < 3; ++s)
            xc[s] = xpt[(256 * s + jc) * 4 + q];
    }

    // Persistent A-frags; zero-init ONCE so lanes l15>=4 stay 0 forever.
    i32x4 Areg[4];
    #pragma unroll
    for (int kk = 0; kk < 4; ++kk) Areg[kk] = (i32x4){0, 0, 0, 0};

    int pb = 0;
    for (int t = 0; t < T_STEPS; ++t) {
        // prefetch xp for t+1 (latency hides under MFMA + gate phase)
        const int tn = (t + 1 < T_STEPS) ? t + 1 : t;
        unsigned short xn_[3];
        {
            const unsigned short* xpt = xp2 + ((size_t)tn * 16 + wg) * (G3 * 4);
            #pragma unroll
            for (int s = 0; s < 3; ++s)
                xn_[s] = xpt[(256 * s + jc) * 4 + q];
        }

        // Masked A-frag read: 16 active lanes, 2 lanes/bank (conflict-free).
        if (l15 < 4) {
            #pragma unroll
            for (int kk = 0; kk < 4; ++kk)
                Areg[kk] = *(const i32x4*)(&hbuf[pb][l15][kk * 64 + q * 16]);
        }

        // int8 matvec: 3 gh-tiles per wave, 2 K-chains each (6 indep chains).
        i32x4 acA[3], acB[3];
        #pragma unroll
        for (int s = 0; s < 3; ++s) { acA[s] = (i32x4){0,0,0,0}; acB[s] = (i32x4){0,0,0,0}; }
        #pragma unroll
        for (int s = 0; s < 3; ++s)
            acA[s] = __builtin_amdgcn_mfma_i32_16x16x64_i8(Areg[0], W[s][0], acA[s], 0, 0, 0);
        #pragma unroll
        for (int s = 0; s < 3; ++s)
            acB[s] = __builtin_amdgcn_mfma_i32_16x16x64_i8(Areg[2], W[s][2], acB[s], 0, 0, 0);
        #pragma unroll
        for (int s = 0; s < 3; ++s)
            acA[s] = __builtin_amdgcn_mfma_i32_16x16x64_i8(Areg[1], W[s][1], acA[s], 0, 0, 0);
        #pragma unroll
        for (int s = 0; s < 3; ++s)
            acB[s] = __builtin_amdgcn_mfma_i32_16x16x64_i8(Areg[3], W[s][3], acB[s], 0, 0, 0);

        // Lane-pack: pure-VALU permlane; lane (q,l15) <- (row q, col l15).
        float P[3];
        #pragma unroll
        for (int s = 0; s < 3; ++s) P[s] = (float)pack4(acA[s] + acB[s]);

        const int pbn = pb ^ 1;
        {
            const float a_r = fmaf(d[0], P[0], bf2f(xc[0]) + bh[0]);
            const float rg  = __builtin_amdgcn_rcpf(
                1.f + __builtin_amdgcn_exp2f(-LOG2E * a_r));
            const float a_z = fmaf(d[1], P[1], bf2f(xc[1]) + bh[1]);
            const float ez  = __builtin_amdgcn_exp2f(-LOG2E * a_z);
            const float zi  = __builtin_amdgcn_rcpf(1.f + ez);     // = z
            const float hng = fmaf(d[2], P[2], bh[2]);
            const float na  = fmaf(rg, hng, bf2f(xc[2]));
            const float e2  = __builtin_amdgcn_exp2f(2.f * LOG2E * na);
            const float th  = 1.f - 2.f * __builtin_amdgcn_rcpf(e2 + 1.f);  // tanh
            const float hv  = zi * fmaf(ez, th, h);                // (1-z)n + zh
            h = hv;
            hbuf[pbn][q][jc] = (signed char)(int)rintf(hv * 127.f);
            out[((size_t)t * NB + wg * 4 + q) * CDIM + jc] = hv;
        }
        // lgkm-only barrier: publish hbuf[pbn]; skip vmcnt(0) drain (out
        // stores + xp prefetch are lane-private, no cross-wave global deps)
        asm volatile("s_waitcnt lgkmcnt(0)\n\ts_barrier" ::: "memory");
        pb = pbn;
        #pragma unroll
        for (int s = 0; s < 3; ++s) xc[s] = xn_[s];
    }
}

// ---------------------------------------------------------------------------
// K3: in-place log_softmax over C=256. One wave per row, 4 rows per block.
// ---------------------------------------------------------------------------
__global__ __launch_bounds__(256) void logsoftmax_rows(float* __restrict__ out)
{
    const int tid  = threadIdx.x;
    const int wv   = tid >> 6, lane = tid & 63;
    const int row  = blockIdx.x * 4 + wv;     // 0..63999
    float* p = out + (size_t)row * CDIM + lane * 4;
    float4 v = *(const float4*)p;

    float m = fmaxf(fmaxf(v.x, v.y), fmaxf(v.z, v.w));
    #pragma unroll
    for (int s = 32; s > 0; s >>= 1) m = fmaxf(m, __shfl_xor(m, s, 64));

    float sum = __builtin_amdgcn_exp2f((v.x - m) * LOG2E)
              + __builtin_amdgcn_exp2f((v.y - m) * LOG2E)
              + __builtin_amdgcn_exp2f((v.z - m) * LOG2E)
              + __builtin_amdgcn_exp2f((v.w - m) * LOG2E);
    #pragma unroll
    for (int s = 32; s > 0; s >>= 1) sum += __shfl_xor(sum, s, 64);

    const float lse = m + __builtin_amdgcn_logf(sum) * 0.69314718055994531f;
    v.x -= lse; v.y -= lse; v.z -= lse; v.w -= lse;
    *(float4*)p = v;
}

// ---------------------------------------------------------------------------
// Workspace layout (bytes):
//   xp2     @ 0           : 1000*768*64*2 = 98,304,000
//   wih_bf  @ 98,304,000  : 786,432*2     =  1,572,864
//   whhq    @ 99,876,864  : 196,608       =    196,608
//   dscale  @ 100,073,472 : 768*4         =      3,072
//   enc_bf  @ 100,076,544 : 65,536,000*2  = 131,072,000  (optional; guarded)
// ---------------------------------------------------------------------------
extern "C" void kernel_launch(void* const* d_in, const int* in_sizes, int n_in,
                              void* d_out, int out_size, void* d_ws, size_t ws_size,
                              hipStream_t stream)
{
    const float* enc = (const float*)d_in[0];   // [1000,64,1024]
    const float* wih = (const float*)d_in[1];   // [768,1024]
    const float* whh = (const float*)d_in[2];   // [768,256]
    const float* bih = (const float*)d_in[3];   // [768]
    const float* bhh = (const float*)d_in[4];   // [768]
    float* out = (float*)d_out;                 // [1000,64,256]

    unsigned short* xp2    = (unsigned short*)d_ws;
    unsigned short* wih_bf = (unsigned short*)((char*)d_ws + 98304000);
    signed char*    whhq   = (signed char*)((char*)d_ws + 99876864);
    float*          dsc    = (float*)((char*)d_ws + 100073472);
    unsigned short* enc_bf = (unsigned short*)((char*)d_ws + 100076544);

    const bool big_ws = (ws_size >= 100076544ULL + 131072000ULL);

    cvt_wih<<<dim3(3072), dim3(256), 0, stream>>>(wih, wih_bf);
    quant_whh<<<dim3(768), dim3(64), 0, stream>>>(whh, whhq, dsc);
    if (big_ws) {
        cvt_enc<<<dim3(32000), dim3(256), 0, stream>>>(enc, enc_bf);
        xproj_gemm_bf<<<dim3(12, 1000), dim3(256), 0, stream>>>(enc_bf, wih_bf, bih, xp2);
    } else {
        xproj_gemm<<<dim3(12, 1000), dim3(256), 0, stream>>>(enc, wih_bf, bih, xp2);
    }
    gru_scan<<<dim3(16), dim3(1024), 0, stream>>>(xp2, whhq, dsc, bhh, out);
    logsoftmax_rows<<<dim3(16000), dim3(256), 0, stream>>>(out);
}